// Round 1
// baseline (1015.471 us; speedup 1.0000x reference)
//
#include <hip/hip_runtime.h>
#include <math.h>

// Problem constants (nanoGPT Head): x[B,T,C] @ W{q,k,v}[C,H] -> causal attn -> out[B,T,H]
#define BB 8
#define TT 4096
#define CC 64
#define HH 128
#define BQ 64
#define BK 64
#define NTH 512
#define LSTR 132   // LDS row stride in floats (128 + 4 pad, keeps 16B alignment)

// ---------------- Kernel 1: QKV projection ----------------
// grid = B*T/8 blocks, 128 threads. Each thread owns one h (0..127) and
// computes q,k,v for 8 consecutive rows. W loads are coalesced and L1/L2-hot.
__global__ __launch_bounds__(128) void qkv_proj(
    const float* __restrict__ x,
    const float* __restrict__ Wq, const float* __restrict__ Wk, const float* __restrict__ Wv,
    float* __restrict__ q, float* __restrict__ k, float* __restrict__ v)
{
    __shared__ __align__(16) float xs[8 * CC];
    const int tid = threadIdx.x;
    const long long row0 = (long long)blockIdx.x * 8;
    // 8 rows * 64 cols = 512 floats = 128 float4 -> one float4 per thread
    ((float4*)xs)[tid] = ((const float4*)(x + row0 * CC))[tid];
    __syncthreads();

    const int h = tid;
    float accq[8], acck[8], accv[8];
#pragma unroll
    for (int r = 0; r < 8; ++r) { accq[r] = 0.f; acck[r] = 0.f; accv[r] = 0.f; }

    for (int c = 0; c < CC; ++c) {
        const float wq = Wq[c * HH + h];
        const float wk = Wk[c * HH + h];
        const float wv = Wv[c * HH + h];
#pragma unroll
        for (int r = 0; r < 8; ++r) {
            const float xv = xs[r * CC + c];   // LDS broadcast (same addr all lanes)
            accq[r] = fmaf(xv, wq, accq[r]);
            acck[r] = fmaf(xv, wk, acck[r]);
            accv[r] = fmaf(xv, wv, accv[r]);
        }
    }
#pragma unroll
    for (int r = 0; r < 8; ++r) {
        const long long o = (row0 + r) * HH + h;
        q[o] = accq[r]; k[o] = acck[r]; v[o] = accv[r];
    }
}

// ---------------- Kernel 2: fp32 flash attention ----------------
// One block per (batch, q-tile of 64). 512 threads.
// LDS: Qs (64x128), KPs (K tile, later reused as P tile), Vs. ~99 KB -> 1 block/CU, 8 waves.
__device__ __forceinline__ void load_tile64(const float* __restrict__ g, float* __restrict__ ls, int row0)
{
    const int tid = threadIdx.x;
#pragma unroll
    for (int i = 0; i < 4; ++i) {
        const int idx = tid + i * NTH;        // 0..2047
        const int r  = idx >> 5;              // 32 float4 per 128-wide row
        const int c4 = idx & 31;
        *(float4*)&ls[r * LSTR + c4 * 4] =
            ((const float4*)(g + (long long)(row0 + r) * HH))[c4];
    }
}

__global__ __launch_bounds__(NTH) void flash_fp32(
    const float* __restrict__ q, const float* __restrict__ k, const float* __restrict__ v,
    float* __restrict__ out)
{
    __shared__ __align__(16) float Qs[BQ * LSTR];
    __shared__ __align__(16) float KPs[BK * LSTR];  // K tile; overwritten with P after S phase
    __shared__ __align__(16) float Vs[BK * LSTR];

    const int tid  = threadIdx.x;
    const int b    = blockIdx.x & (BB - 1);
    const int qt   = (TT / BQ) - 1 - (blockIdx.x >> 3);  // heavy (large-qt) blocks first
    const long long base = (long long)b * TT * HH;
    const int q0   = qt * BQ;

    const int rowg = tid >> 4;        // 0..31 : rows rowg*2, rowg*2+1
    const int colg = tid & 15;        // 0..15 : S cols colg*4.., O cols colg*8..
    const int r0   = rowg * 2;

    load_tile64(q + base, Qs, q0);

    float o[2][8];
#pragma unroll
    for (int i = 0; i < 2; ++i)
#pragma unroll
        for (int jj = 0; jj < 8; ++jj) o[i][jj] = 0.f;
    float m[2] = { -INFINITY, -INFINITY };
    float l[2] = { 0.f, 0.f };

    const float scale = 0.08838834764831845f;  // 128^-0.5

    for (int kt = 0; kt <= qt; ++kt) {
        const int k0 = kt * BK;
        __syncthreads();                         // prior-iter readers of KPs/Vs done
        load_tile64(k + base, KPs, k0);
        load_tile64(v + base, Vs, k0);
        __syncthreads();                         // tiles (and Qs on iter 0) visible

        // ---- S = Q K^T (2x4 micro-tile per thread) ----
        float s[2][4];
#pragma unroll
        for (int i = 0; i < 2; ++i)
#pragma unroll
            for (int j = 0; j < 4; ++j) s[i][j] = 0.f;

        for (int d = 0; d < HH; d += 4) {
            const float4 qa = *(const float4*)&Qs[(r0 + 0) * LSTR + d];
            const float4 qb = *(const float4*)&Qs[(r0 + 1) * LSTR + d];
#pragma unroll
            for (int j = 0; j < 4; ++j) {
                const float4 kv = *(const float4*)&KPs[(colg * 4 + j) * LSTR + d];
                s[0][j] = fmaf(qa.x, kv.x, fmaf(qa.y, kv.y, fmaf(qa.z, kv.z, fmaf(qa.w, kv.w, s[0][j]))));
                s[1][j] = fmaf(qb.x, kv.x, fmaf(qb.y, kv.y, fmaf(qb.z, kv.z, fmaf(qb.w, kv.w, s[1][j]))));
            }
        }

        // scale + causal mask (diagonal tile only; q0==k0 there)
#pragma unroll
        for (int i = 0; i < 2; ++i)
#pragma unroll
            for (int j = 0; j < 4; ++j) {
                s[i][j] *= scale;
                if (kt == qt && (colg * 4 + j) > (r0 + i)) s[i][j] = -INFINITY;
            }

        __syncthreads();                         // all S reads of KPs done before P write

        // ---- online softmax + write P into KPs ----
        float alpha[2];
#pragma unroll
        for (int i = 0; i < 2; ++i) {
            float rmax = fmaxf(fmaxf(s[i][0], s[i][1]), fmaxf(s[i][2], s[i][3]));
#pragma unroll
            for (int mask = 1; mask < 16; mask <<= 1)
                rmax = fmaxf(rmax, __shfl_xor(rmax, mask));
            const float mnew = fmaxf(m[i], rmax);
            alpha[i] = __expf(m[i] - mnew);      // 0 on first tile (m=-inf)
            float rsum = 0.f;
#pragma unroll
            for (int j = 0; j < 4; ++j) {
                const float p = __expf(s[i][j] - mnew);
                s[i][j] = p;
                rsum += p;
            }
#pragma unroll
            for (int mask = 1; mask < 16; mask <<= 1)
                rsum += __shfl_xor(rsum, mask);
            l[i] = l[i] * alpha[i] + rsum;
            m[i] = mnew;
#pragma unroll
            for (int jj = 0; jj < 8; ++jj) o[i][jj] *= alpha[i];
#pragma unroll
            for (int j = 0; j < 4; ++j)
                KPs[(r0 + i) * LSTR + colg * 4 + j] = s[i][j];
        }

        __syncthreads();                         // P visible

        // ---- O += P V (rows r0..r0+1, cols colg*8..+7) ----
        for (int j = 0; j < BK; ++j) {
            const float p0 = KPs[(r0 + 0) * LSTR + j];   // broadcast across colg
            const float p1 = KPs[(r0 + 1) * LSTR + j];
            const float4 va = *(const float4*)&Vs[j * LSTR + colg * 8];
            const float4 vb = *(const float4*)&Vs[j * LSTR + colg * 8 + 4];
            o[0][0] = fmaf(p0, va.x, o[0][0]); o[0][1] = fmaf(p0, va.y, o[0][1]);
            o[0][2] = fmaf(p0, va.z, o[0][2]); o[0][3] = fmaf(p0, va.w, o[0][3]);
            o[0][4] = fmaf(p0, vb.x, o[0][4]); o[0][5] = fmaf(p0, vb.y, o[0][5]);
            o[0][6] = fmaf(p0, vb.z, o[0][6]); o[0][7] = fmaf(p0, vb.w, o[0][7]);
            o[1][0] = fmaf(p1, va.x, o[1][0]); o[1][1] = fmaf(p1, va.y, o[1][1]);
            o[1][2] = fmaf(p1, va.z, o[1][2]); o[1][3] = fmaf(p1, va.w, o[1][3]);
            o[1][4] = fmaf(p1, vb.x, o[1][4]); o[1][5] = fmaf(p1, vb.y, o[1][5]);
            o[1][6] = fmaf(p1, vb.z, o[1][6]); o[1][7] = fmaf(p1, vb.w, o[1][7]);
        }
    }

    // ---- epilogue: divide by l, write out ----
#pragma unroll
    for (int i = 0; i < 2; ++i) {
        const float inv = 1.f / l[i];
        float* op = out + base + (long long)(q0 + r0 + i) * HH + colg * 8;
        float4 w0 = make_float4(o[i][0] * inv, o[i][1] * inv, o[i][2] * inv, o[i][3] * inv);
        float4 w1 = make_float4(o[i][4] * inv, o[i][5] * inv, o[i][6] * inv, o[i][7] * inv);
        *(float4*)(op)     = w0;
        *(float4*)(op + 4) = w1;
    }
}

extern "C" void kernel_launch(void* const* d_in, const int* in_sizes, int n_in,
                              void* d_out, int out_size, void* d_ws, size_t ws_size,
                              hipStream_t stream)
{
    const float* x  = (const float*)d_in[0];
    const float* Wq = (const float*)d_in[1];
    const float* Wk = (const float*)d_in[2];
    const float* Wv = (const float*)d_in[3];
    float* out = (float*)d_out;

    const long long n = (long long)BB * TT * HH;   // 4,194,304 elems each
    float* q = (float*)d_ws;
    float* k = q + n;
    float* v = k + n;

    qkv_proj<<<BB * TT / 8, 128, 0, stream>>>(x, Wq, Wk, Wv, q, k, v);
    flash_fp32<<<BB * (TT / BQ), NTH, 0, stream>>>(q, k, v, out);
}

// Round 2
// 257.098 us; speedup vs baseline: 3.9497x; 3.9497x over previous
//
#include <hip/hip_runtime.h>
#include <math.h>

// nanoGPT Head: x[B,T,C] @ W{q,k,v}[C,H] -> causal softmax(QK^T/sqrt(H)) V
#define BB 8
#define TT 4096
#define CC 64
#define HH 128
#define BQ 64          // Q rows per block (4 waves x 16)
#define BK 64          // keys per tile
#define NTH 256
#define KSTR 136       // K-tile LDS row stride in bf16 (128 + 8 pad -> 2-way banks)
#define VSTR 72        // Vt-tile LDS row stride in bf16 (64 + 8 pad)
#define PSTR 72        // P LDS row stride in bf16

typedef __attribute__((ext_vector_type(8))) short short8;   // 8 bf16 = 4 VGPRs (MFMA A/B frag)
typedef __attribute__((ext_vector_type(4))) float floatx4;  // MFMA C/D frag

__device__ __forceinline__ unsigned short f2bf(float f) {
    union { float f; unsigned int u; } un; un.f = f;
    unsigned int r = un.u + 0x7FFF + ((un.u >> 16) & 1);   // RNE
    return (unsigned short)(r >> 16);
}

// ---------------- Kernel 1: QKV projection (fp32 in, bf16 out; V transposed) ----------------
// q,k: [B,T,H] bf16.  vt: [B,H,T] bf16 (so PV B-operand LDS reads are contiguous).
__global__ __launch_bounds__(128) void qkv_proj_bf16(
    const float* __restrict__ x,
    const float* __restrict__ Wq, const float* __restrict__ Wk, const float* __restrict__ Wv,
    unsigned short* __restrict__ qb, unsigned short* __restrict__ kb, unsigned short* __restrict__ vtb)
{
    __shared__ __align__(16) float xs[8 * CC];
    const int tid = threadIdx.x;
    const long long row0 = (long long)blockIdx.x * 8;
    ((float4*)xs)[tid] = ((const float4*)(x + row0 * CC))[tid];
    __syncthreads();

    const int h = tid;
    float accq[8], acck[8], accv[8];
#pragma unroll
    for (int r = 0; r < 8; ++r) { accq[r] = 0.f; acck[r] = 0.f; accv[r] = 0.f; }

    for (int c = 0; c < CC; ++c) {
        const float wq = Wq[c * HH + h];
        const float wk = Wk[c * HH + h];
        const float wv = Wv[c * HH + h];
#pragma unroll
        for (int r = 0; r < 8; ++r) {
            const float xv = xs[r * CC + c];
            accq[r] = fmaf(xv, wq, accq[r]);
            acck[r] = fmaf(xv, wk, acck[r]);
            accv[r] = fmaf(xv, wv, accv[r]);
        }
    }
    const int b  = (int)(row0 >> 12);        // T = 4096
    const int t0 = (int)(row0 & (TT - 1));
#pragma unroll
    for (int r = 0; r < 8; ++r) {
        const long long o = (row0 + r) * HH + h;
        qb[o] = f2bf(accq[r]);
        kb[o] = f2bf(acck[r]);
        vtb[((long long)b * HH + h) * TT + t0 + r] = f2bf(accv[r]);
    }
}

// ---------------- Kernel 2: bf16 MFMA flash attention ----------------
// One block = (batch, 64-query tile). 4 waves, each owns 16 query rows.
// mfma_f32_16x16x32_bf16 layouts (HW-verified):
//   A: m = lane&15, k = (lane>>4)*8 + j
//   B: n = lane&15, k = (lane>>4)*8 + j      (B[k][n], i.e. reads K / Vt rows)
//   C/D: col = lane&15, row = (lane>>4)*4 + reg
__global__ __launch_bounds__(NTH) void flash_mfma(
    const unsigned short* __restrict__ qb,
    const unsigned short* __restrict__ kb,
    const unsigned short* __restrict__ vtb,
    float* __restrict__ out)
{
    __shared__ __align__(16) unsigned short Ks[BK * KSTR];    // K tile, key-major
    __shared__ __align__(16) unsigned short Vts[HH * VSTR];   // V^T tile, d-major
    __shared__ __align__(16) unsigned short Ps[4 * 16 * PSTR];// per-wave P tiles

    const int tid  = threadIdx.x;
    const int w    = tid >> 6;
    const int lane = tid & 63;
    const int quad = lane >> 4;
    const int lr   = lane & 15;

    const int b  = blockIdx.x & (BB - 1);
    const int qt = (TT / BQ) - 1 - (blockIdx.x >> 3);   // heavy blocks first
    const int q0 = qt * BQ;
    const long long baset = (long long)b * TT;

    // Q fragments (A-operand), row = q0 + w*16 + lr, resident for the whole loop
    short8 aq[4];
    {
        const unsigned short* qrp = qb + (baset + q0 + w * 16 + lr) * HH + quad * 8;
#pragma unroll
        for (int f = 0; f < 4; ++f)
            aq[f] = *(const short8*)(qrp + f * 32);
    }

    floatx4 o_acc[8];
#pragma unroll
    for (int dt = 0; dt < 8; ++dt) o_acc[dt] = (floatx4)0.f;
    float m_i[4] = {-INFINITY, -INFINITY, -INFINITY, -INFINITY};
    float l_i[4] = {0.f, 0.f, 0.f, 0.f};

    const float scale = 0.08838834764831845f;   // 128^-0.5
    unsigned short* Pw = Ps + w * 16 * PSTR;

    for (int kt = 0; kt <= qt; ++kt) {
        const int k0 = kt * BK;
        __syncthreads();   // prior-iter readers of Ks/Vts done
        // stage K tile: 64 rows x 128 bf16 (1024 float4)
#pragma unroll
        for (int it = 0; it < 4; ++it) {
            const int idx = tid + it * NTH;
            const int row = idx >> 4, c = idx & 15;
            const float4* gk = (const float4*)(kb + (baset + k0 + row) * HH);
            *(float4*)&Ks[row * KSTR + c * 8] = gk[c];
        }
        // stage Vt tile: 128 d-rows x 64 bf16 (1024 float4)
#pragma unroll
        for (int it = 0; it < 4; ++it) {
            const int idx = tid + it * NTH;
            const int d = idx >> 3, c = idx & 7;
            const float4* gv = (const float4*)(vtb + ((long long)b * HH + d) * TT + k0);
            *(float4*)&Vts[d * VSTR + c * 8] = gv[c];
        }
        __syncthreads();

        // ---- S = Q K^T : 4 key-subtiles x 4 d-steps ----
        floatx4 s_acc[4];
#pragma unroll
        for (int t = 0; t < 4; ++t) s_acc[t] = (floatx4)0.f;
#pragma unroll
        for (int f = 0; f < 4; ++f) {
#pragma unroll
            for (int t = 0; t < 4; ++t) {
                const short8 bk = *(const short8*)&Ks[(t * 16 + lr) * KSTR + f * 32 + quad * 8];
                s_acc[t] = __builtin_amdgcn_mfma_f32_16x16x32_bf16(aq[f], bk, s_acc[t], 0, 0, 0);
            }
        }

        // ---- online softmax (rows quad*4+r, cols 16t+lr) ----
        float alpha[4];
        float pv[4][4];
#pragma unroll
        for (int r = 0; r < 4; ++r) {
            const int qr = q0 + w * 16 + quad * 4 + r;
            float sv[4];
#pragma unroll
            for (int t = 0; t < 4; ++t) {
                sv[t] = s_acc[t][r] * scale;
                if (k0 + t * 16 + lr > qr) sv[t] = -INFINITY;   // only bites on diagonal tile
            }
            float rmax = fmaxf(fmaxf(sv[0], sv[1]), fmaxf(sv[2], sv[3]));
#pragma unroll
            for (int msk = 1; msk < 16; msk <<= 1)
                rmax = fmaxf(rmax, __shfl_xor(rmax, msk));
            const float mnew = fmaxf(m_i[r], rmax);
            alpha[r] = __expf(m_i[r] - mnew);                  // 0 on first tile
            float rsum = 0.f;
#pragma unroll
            for (int t = 0; t < 4; ++t) {
                const float p = __expf(sv[t] - mnew);
                pv[r][t] = p;
                rsum += p;
            }
#pragma unroll
            for (int msk = 1; msk < 16; msk <<= 1)
                rsum += __shfl_xor(rsum, msk);
            l_i[r] = l_i[r] * alpha[r] + rsum;
            m_i[r] = mnew;
        }
#pragma unroll
        for (int dt = 0; dt < 8; ++dt) {
            o_acc[dt][0] *= alpha[0]; o_acc[dt][1] *= alpha[1];
            o_acc[dt][2] *= alpha[2]; o_acc[dt][3] *= alpha[3];
        }
        // write P (C-layout) to LDS as bf16 for A-layout reload
#pragma unroll
        for (int r = 0; r < 4; ++r)
#pragma unroll
            for (int t = 0; t < 4; ++t)
                Pw[(quad * 4 + r) * PSTR + t * 16 + lr] = f2bf(pv[r][t]);
        __syncthreads();

        // ---- O += P V : A = P (16x64), B = Vt rows ----
        const short8 ap0 = *(const short8*)&Pw[lr * PSTR + quad * 8];
        const short8 ap1 = *(const short8*)&Pw[lr * PSTR + 32 + quad * 8];
#pragma unroll
        for (int dt = 0; dt < 8; ++dt) {
            const short8 bv0 = *(const short8*)&Vts[(dt * 16 + lr) * VSTR + quad * 8];
            const short8 bv1 = *(const short8*)&Vts[(dt * 16 + lr) * VSTR + 32 + quad * 8];
            o_acc[dt] = __builtin_amdgcn_mfma_f32_16x16x32_bf16(ap0, bv0, o_acc[dt], 0, 0, 0);
            o_acc[dt] = __builtin_amdgcn_mfma_f32_16x16x32_bf16(ap1, bv1, o_acc[dt], 0, 0, 0);
        }
    }

    // ---- epilogue: divide by l, write out (fp32) ----
#pragma unroll
    for (int r = 0; r < 4; ++r) {
        const float inv = 1.f / l_i[r];
        float* op = out + (baset + q0 + w * 16 + quad * 4 + r) * HH;
#pragma unroll
        for (int dt = 0; dt < 8; ++dt)
            op[dt * 16 + lr] = o_acc[dt][r] * inv;
    }
}

extern "C" void kernel_launch(void* const* d_in, const int* in_sizes, int n_in,
                              void* d_out, int out_size, void* d_ws, size_t ws_size,
                              hipStream_t stream)
{
    const float* x  = (const float*)d_in[0];
    const float* Wq = (const float*)d_in[1];
    const float* Wk = (const float*)d_in[2];
    const float* Wv = (const float*)d_in[3];
    float* out = (float*)d_out;

    const long long n = (long long)BB * TT * HH;   // 4,194,304 elems
    unsigned short* qb  = (unsigned short*)d_ws;
    unsigned short* kb  = qb + n;
    unsigned short* vtb = kb + n;

    qkv_proj_bf16<<<BB * TT / 8, 128, 0, stream>>>(x, Wq, Wk, Wv, qb, kb, vtb);
    flash_mfma<<<BB * (TT / BQ), NTH, 0, stream>>>(qb, kb, vtb, out);
}